// Round 5
// baseline (351.284 us; speedup 1.0000x reference)
//
#include <hip/hip_runtime.h>

// Inputs are f32 (verified: R2-R5 passed via runtime-detect f32 path; reference
// declares float32 and output absmax matched at f32 write-back). bf16 staging
// internally; f32 accumulate; f32 out.
//
// Session notes:
// - spmm_dual4 (1 row/wave, wave-uniform) = 113 us is the proven best; the
//   4-rows/wave (125) and persistent co-resident (127) variants are both worse.
//   FETCH pinned ~383 MB (compulsory per-XCD refetch), rate pinned 3.4-3.9 TB/s
//   => random-512B-gather roofline. Do not restructure spmm without a byte cut.
// - DO NOT fuse colsum->sigmoid via atomicAdd into a 256-float region:
//   320K far-atomics serialize ~160 us (R3 disaster). Partial buffer + second
//   pass is the right structure. 256 atomics (sigv_fused) is fine.
// - R3/R4 accounting: prep + dp2 + gaps ~ 184 us; non-spmm total ~222 us.
//   Per-block GEMM setup (W1 fragment loads) and launch gaps are significant.

// ---------- bf16 bit helpers ----------
__device__ __forceinline__ float b2f(unsigned short s) {
    union { unsigned int u; float f; } c; c.u = ((unsigned int)s) << 16; return c.f;
}
__device__ __forceinline__ unsigned short f2b(float f) {
    union { float f; unsigned int u; } c; c.f = f;
    unsigned int u = c.u;
    unsigned int r = u + 0x7FFFu + ((u >> 16) & 1u);   // RNE
    return (unsigned short)(r >> 16);
}
__device__ __forceinline__ unsigned int pack2(float lo, float hi) {
    return ((unsigned int)f2b(hi) << 16) | f2b(lo);
}
__device__ __forceinline__ void fma8(float* a, float v, uint4 w) {
    a[0] = fmaf(v, b2f((unsigned short)w.x), a[0]);
    a[1] = fmaf(v, b2f((unsigned short)(w.x >> 16)), a[1]);
    a[2] = fmaf(v, b2f((unsigned short)w.y), a[2]);
    a[3] = fmaf(v, b2f((unsigned short)(w.y >> 16)), a[3]);
    a[4] = fmaf(v, b2f((unsigned short)w.z), a[4]);
    a[5] = fmaf(v, b2f((unsigned short)(w.z >> 16)), a[5]);
    a[6] = fmaf(v, b2f((unsigned short)w.w), a[6]);
    a[7] = fmaf(v, b2f((unsigned short)(w.w >> 16)), a[7]);
}

typedef __attribute__((ext_vector_type(8))) short bf16x8;
typedef __attribute__((ext_vector_type(4))) float f32x4;

#define T_TILES 5

// ---------- K1: fused prep: rowptr | W1 -> bf16 | x/x_tilde -> interleaved bf16 | zero done ----------
// xint layout: node row = 512 B: [x 128 bf16][x_tilde 128 bf16]
// Conversion: 16 f32 -> 16 bf16 per thread (64B read / 32B write).
__global__ __launch_bounds__(256) void prep(
    const int* __restrict__ row, int* __restrict__ rp, int n, int e, int rb,
    const float* __restrict__ w1, unsigned short* __restrict__ w1b, int pb,
    const float* __restrict__ x, const float* __restrict__ xt,
    unsigned short* __restrict__ xint, int total16, int halfcb,
    unsigned int* __restrict__ done)
{
    int b = blockIdx.x, tid = threadIdx.x;
    int zb = rb + pb + 2 * halfcb;
    if (b == zb) {                                  // --- zero done counter ---
        if (tid == 0) *done = 0u;
        return;
    }
    if (b < rb) {                                   // --- build row_ptr ---
        int i = b * 256 + tid;
        if (i > e) return;
        if (i == 0) {
            int r1 = row[0];
            for (int rr = 0; rr <= r1; ++rr) rp[rr] = 0;
        } else if (i == e) {
            int r0 = row[e - 1];
            for (int rr = r0 + 1; rr <= n; ++rr) rp[rr] = e;
        } else {
            int r0 = row[i - 1], r1 = row[i];
            for (int rr = r0 + 1; rr <= r1; ++rr) rp[rr] = i;
        }
    } else if (b < rb + pb) {                       // --- W1 -> bf16 ---
        int i = (b - rb) * 256 + tid;               // 0..32767
        if (i < 32768) w1b[i] = f2b(w1[i]);
    } else {                                        // --- x conversion (interleaved) ---
        int cb = b - rb - pb;
        int which = (cb >= halfcb) ? 1 : 0;
        int j = (cb - which * halfcb) * 256 + tid;  // 16-elem chunk index
        if (j >= total16) return;
        const float* s = which ? xt : x;
        int node = j >> 3, sub16 = j & 7;
        const float4* p = (const float4*)s + (size_t)j * 4;
        float4 a0 = p[0], a1 = p[1], a2 = p[2], a3 = p[3];
        uint4 o0, o1;
        o0.x = pack2(a0.x, a0.y);  o0.y = pack2(a0.z, a0.w);
        o0.z = pack2(a1.x, a1.y);  o0.w = pack2(a1.z, a1.w);
        o1.x = pack2(a2.x, a2.y);  o1.y = pack2(a2.z, a2.w);
        o1.z = pack2(a3.x, a3.y);  o1.w = pack2(a3.z, a3.w);
        unsigned short* dst = xint + (size_t)node * 256 + which * 128 + sub16 * 16;
        *(uint4*)(dst) = o0;
        *(uint4*)(dst + 8) = o1;
    }
}

// ---------- K2: dual SpMM; col/vals preloaded per 64-edge chunk, 16 edges/iter ----------
// lane = g*16 + l: group g handles edges {base+4u+g}, lane l handles dims [8l,8l+8)
// PROVEN BEST (113 us). Wave-uniform trip count is essential. DO NOT TOUCH.
__global__ __launch_bounds__(256) void spmm_dual4(
    const unsigned short* __restrict__ xint, const float* __restrict__ vals,
    const int* __restrict__ col, const int* __restrict__ row_ptr,
    unsigned short* __restrict__ aggx, unsigned short* __restrict__ aggt, int n)
{
    int wave = threadIdx.x >> 6;
    int lane = threadIdx.x & 63;
    int g = lane >> 4, l = lane & 15;
    int r = blockIdx.x * 4 + wave;
    if (r >= n) return;
    int e0 = row_ptr[r], e1 = row_ptr[r + 1];
    float ax[8], at[8];
#pragma unroll
    for (int d = 0; d < 8; ++d) { ax[d] = 0.f; at[d] = 0.f; }
    for (int chunk = e0; chunk < e1; chunk += 64) {
        int m = e1 - chunk; if (m > 64) m = 64;     // edges in this chunk
        int ce = chunk + (lane < m ? lane : m - 1); // coalesced preload (clamped)
        int cc = col[ce];
        float cv = (lane < m) ? vals[ce] : 0.f;
        for (int base = 0; base < m; base += 16) {
            uint4 xw[4], tw[4];
            float fv[4];
#pragma unroll
            for (int u = 0; u < 4; ++u) {
                int idx = base + 4 * u + g;
                int idc = idx < m ? idx : m - 1;    // clamp: duplicate line is cache-hot
                int c  = __shfl(cc, idc, 64);
                float v = __shfl(cv, idc, 64);
                fv[u] = (idx < m) ? v : 0.f;
                const uint4* p = (const uint4*)(xint + (size_t)c * 256);
                xw[u] = p[l];
                tw[u] = p[16 + l];
            }
#pragma unroll
            for (int u = 0; u < 4; ++u) { fma8(ax, fv[u], xw[u]); fma8(at, fv[u], tw[u]); }
        }
    }
#pragma unroll
    for (int d = 0; d < 8; ++d) {
        ax[d] += __shfl_xor(ax[d], 16, 64);
        ax[d] += __shfl_xor(ax[d], 32, 64);
        at[d] += __shfl_xor(at[d], 16, 64);
        at[d] += __shfl_xor(at[d], 32, 64);
    }
    if (g == 0) {
        uint4 o;
        o.x = pack2(ax[0], ax[1]); o.y = pack2(ax[2], ax[3]);
        o.z = pack2(ax[4], ax[5]); o.w = pack2(ax[6], ax[7]);
        ((uint4*)(aggx + (size_t)r * 128))[l] = o;
    } else if (g == 1) {
        uint4 o;
        o.x = pack2(at[0], at[1]); o.y = pack2(at[2], at[3]);
        o.z = pack2(at[4], at[5]); o.w = pack2(at[6], at[7]);
        ((uint4*)(aggt + (size_t)r * 128))[l] = o;
    }
}

// ---------- K3: GEMM + colsum; W1 resident; transposed atomic-free partials ----------
// C/D layout: col = nl, row = quad*4 + r. Column sum => sum over r, then quad bits.
// partial layout: [out_dim 256][block nb]  (coalesced for the reducer)
__global__ __launch_bounds__(256) void gemm_colsum3(
    const short* __restrict__ aggb, const short* __restrict__ w1,
    const float* __restrict__ pa, float* __restrict__ partial, int ntiles, int nb)
{
    int tid = threadIdx.x;
    int w = tid >> 6, lane = tid & 63;
    int nl = lane & 15, quad = lane >> 4;
    const short* brow = w1 + ((size_t)(4 * w) * 16 + nl) * 128 + quad * 8;
    bf16x8 bf[4][4];
#pragma unroll
    for (int j = 0; j < 4; ++j)
#pragma unroll
        for (int k = 0; k < 4; ++k)
            bf[j][k] = *(const bf16x8*)(brow + j * 2048 + k * 32);
    float aslope = pa[0];
    float cs[4] = {0.f, 0.f, 0.f, 0.f};
    int t0 = blockIdx.x * T_TILES;
    int nt = ntiles - t0; if (nt > T_TILES) nt = T_TILES;
    for (int i = 0; i < nt; ++i) {
        const short* arow = aggb + ((size_t)(t0 + i) * 16 + nl) * 128 + quad * 8;
        bf16x8 af[4];
#pragma unroll
        for (int k = 0; k < 4; ++k) af[k] = *(const bf16x8*)(arow + k * 32);
        f32x4 acc[4];
#pragma unroll
        for (int j = 0; j < 4; ++j) acc[j] = (f32x4){0.f, 0.f, 0.f, 0.f};
#pragma unroll
        for (int k = 0; k < 4; ++k)
#pragma unroll
            for (int j = 0; j < 4; ++j)
                acc[j] = __builtin_amdgcn_mfma_f32_16x16x32_bf16(af[k], bf[j][k], acc[j], 0, 0, 0);
#pragma unroll
        for (int j = 0; j < 4; ++j)
#pragma unroll
            for (int r = 0; r < 4; ++r) {
                float z = acc[j][r];
                cs[j] += (z >= 0.f) ? z : aslope * z;
            }
    }
#pragma unroll
    for (int j = 0; j < 4; ++j) {
        cs[j] += __shfl_xor(cs[j], 16, 64);   // reduce rows: quad bits only
        cs[j] += __shfl_xor(cs[j], 32, 64);
    }
    if (quad == 0)
#pragma unroll
        for (int j = 0; j < 4; ++j)
            partial[(size_t)((4 * w + j) * 16 + nl) * nb + blockIdx.x] = cs[j];
}

// ---------- K4: fused reduce+sigmoid -> s, then v = w_bil @ s ----------
// 256 blocks (one per dim), all co-resident (<= 256 CUs) => spin is safe.
// Exactly 256 far-atomics total (NOT the R3 pattern).
__global__ __launch_bounds__(256) void sigv_fused(
    const float* __restrict__ partial, int nb, const float* __restrict__ wbil,
    float* __restrict__ svec, unsigned int* __restrict__ done,
    float* __restrict__ v, float invN)
{
    __shared__ float l[256];
    int d = blockIdx.x, tid = threadIdx.x;
    float s = 0.f;
    for (int i = tid; i < nb; i += 256)
        s += partial[(size_t)d * nb + i];
    l[tid] = s;
    __syncthreads();
    for (int o = 128; o > 0; o >>= 1) {
        if (tid < o) l[tid] += l[tid + o];
        __syncthreads();
    }
    if (tid == 0) {
        float sv = 1.f / (1.f + __expf(-l[0] * invN));
        __hip_atomic_store(&svec[d], sv, __ATOMIC_RELEASE, __HIP_MEMORY_SCOPE_AGENT);
        __hip_atomic_fetch_add(done, 1u, __ATOMIC_RELEASE, __HIP_MEMORY_SCOPE_AGENT);
        // spin until all 256 dims published
        while (__hip_atomic_load(done, __ATOMIC_ACQUIRE, __HIP_MEMORY_SCOPE_AGENT) < 256u)
            __builtin_amdgcn_s_sleep(1);
    }
    __syncthreads();
    // all s values now visible; compute v[d] = sum_j wbil[d][j] * s[j]
    float sj = __hip_atomic_load(&svec[tid], __ATOMIC_ACQUIRE, __HIP_MEMORY_SCOPE_AGENT);
    l[tid] = wbil[(size_t)d * 256 + tid] * sj;
    __syncthreads();
    for (int o = 128; o > 0; o >>= 1) {
        if (tid < o) l[tid] += l[tid + o];
        __syncthreads();
    }
    if (tid == 0) v[d] = l[0];
}

// ---------- K5: GEMM + dot with v for BOTH matrices; W1/v setup amortized ----------
__global__ __launch_bounds__(256) void gemm_dp_both(
    const short* __restrict__ aggx, const short* __restrict__ aggt,
    const short* __restrict__ w1, const float* __restrict__ pa,
    const float* __restrict__ v, float* __restrict__ out, int ntiles, int N)
{
    __shared__ float dpbuf[4][T_TILES * 16];
    int tid = threadIdx.x;
    int w = tid >> 6, lane = tid & 63;
    int nl = lane & 15, quad = lane >> 4;
    const short* brow = w1 + ((size_t)(4 * w) * 16 + nl) * 128 + quad * 8;
    bf16x8 bf[4][4];
#pragma unroll
    for (int j = 0; j < 4; ++j)
#pragma unroll
        for (int k = 0; k < 4; ++k)
            bf[j][k] = *(const bf16x8*)(brow + j * 2048 + k * 32);
    float vreg[4];
#pragma unroll
    for (int j = 0; j < 4; ++j) vreg[j] = v[(4 * w + j) * 16 + nl];
    float aslope = pa[0];
    int t0 = blockIdx.x * T_TILES;
    int nt = ntiles - t0; if (nt > T_TILES) nt = T_TILES;
    for (int mat = 0; mat < 2; ++mat) {
        const short* agg = mat ? aggt : aggx;
        for (int i = 0; i < nt; ++i) {
            const short* arow = agg + ((size_t)(t0 + i) * 16 + nl) * 128 + quad * 8;
            bf16x8 af[4];
#pragma unroll
            for (int k = 0; k < 4; ++k) af[k] = *(const bf16x8*)(arow + k * 32);
            f32x4 acc[4];
#pragma unroll
            for (int j = 0; j < 4; ++j) acc[j] = (f32x4){0.f, 0.f, 0.f, 0.f};
#pragma unroll
            for (int k = 0; k < 4; ++k)
#pragma unroll
                for (int j = 0; j < 4; ++j)
                    acc[j] = __builtin_amdgcn_mfma_f32_16x16x32_bf16(af[k], bf[j][k], acc[j], 0, 0, 0);
            float p[4] = {0.f, 0.f, 0.f, 0.f};
#pragma unroll
            for (int j = 0; j < 4; ++j)
#pragma unroll
                for (int r = 0; r < 4; ++r) {
                    float z = acc[j][r];
                    float h = (z >= 0.f) ? z : aslope * z;
                    p[r] = fmaf(h, vreg[j], p[r]);
                }
#pragma unroll
            for (int r = 0; r < 4; ++r) {   // reduce over nl bits (16 cols of the slice)
                p[r] += __shfl_xor(p[r], 1, 64);
                p[r] += __shfl_xor(p[r], 2, 64);
                p[r] += __shfl_xor(p[r], 4, 64);
                p[r] += __shfl_xor(p[r], 8, 64);
            }
            if (nl == 0)
#pragma unroll
                for (int r = 0; r < 4; ++r)
                    dpbuf[w][i * 16 + quad * 4 + r] = p[r];
        }
        __syncthreads();
        int nloc = nt * 16;
        for (int idx = tid; idx < nloc; idx += 256) {
            float s = dpbuf[0][idx] + dpbuf[1][idx] + dpbuf[2][idx] + dpbuf[3][idx];
            out[(size_t)mat * N + (size_t)t0 * 16 + idx] = s;
        }
        __syncthreads();   // protect dpbuf reuse by mat=1
    }
}

extern "C" void kernel_launch(void* const* d_in, const int* in_sizes, int n_in,
                              void* d_out, int out_size, void* d_ws, size_t ws_size,
                              hipStream_t stream) {
    const float* x    = (const float*)d_in[0];
    const float* xt   = (const float*)d_in[1];
    const float* vals = (const float*)d_in[2];
    const int* row    = (const int*)d_in[3];
    const int* col    = (const int*)d_in[4];
    const float* w1   = (const float*)d_in[5];
    const float* pa   = (const float*)d_in[6];
    const float* wb   = (const float*)d_in[7];

    const int N = in_sizes[0] / 128;
    const int E = in_sizes[2];
    const int ntiles = (N + 15) / 16;
    const int cs_blocks = (ntiles + T_TILES - 1) / T_TILES;

    char* ws = (char*)d_ws;
    size_t off = 0;
    auto alloc = [&](size_t bytes) { char* p = ws + off; off = (off + bytes + 255) & ~(size_t)255; return p; };
    int* row_ptr         = (int*)alloc((size_t)(N + 1) * 4);
    unsigned short* aggx = (unsigned short*)alloc((size_t)N * 128 * 2);
    unsigned short* aggt = (unsigned short*)alloc((size_t)N * 128 * 2);
    unsigned short* w1b  = (unsigned short*)alloc(32768 * 2);
    float* partial       = (float*)alloc((size_t)cs_blocks * 256 * 4);
    float* svec          = (float*)alloc(256 * 4);
    float* vvec          = (float*)alloc(256 * 4);
    unsigned int* done   = (unsigned int*)alloc(256);
    unsigned short* xint = (unsigned short*)alloc((size_t)N * 256 * 2);  // x|xt interleaved bf16

    int rb = (E + 1 + 255) / 256;
    int pb = 128;
    int total16 = (N * 128) / 16;
    int halfcb = (total16 + 255) / 256;
    prep<<<rb + pb + 2 * halfcb + 1, 256, 0, stream>>>(
        row, row_ptr, N, E, rb, w1, w1b, pb, x, xt, xint, total16, halfcb, done);

    spmm_dual4<<<(N + 3) / 4, 256, 0, stream>>>(xint, vals, col, row_ptr, aggx, aggt, N);

    gemm_colsum3<<<cs_blocks, 256, 0, stream>>>(
        (const short*)aggx, (const short*)w1b, pa, partial, ntiles, cs_blocks);

    sigv_fused<<<256, 256, 0, stream>>>(
        partial, cs_blocks, wb, svec, done, vvec, 1.0f / (float)N);

    gemm_dp_both<<<cs_blocks, 256, 0, stream>>>(
        (const short*)aggx, (const short*)aggt, (const short*)w1b, pa, vvec,
        (float*)d_out, ntiles, N);
}

// Round 6
// 344.098 us; speedup vs baseline: 1.0209x; 1.0209x over previous
//
#include <hip/hip_runtime.h>

// Inputs are f32 (verified: R2-R5 passed via runtime-detect f32 path; reference
// declares float32 and output absmax matched at f32 write-back). bf16 staging
// internally; f32 accumulate; f32 out.
//
// Session notes:
// - spmm_dual4 (1 row/wave, wave-uniform) = 113 us is the proven best; the
//   4-rows/wave (125) and persistent co-resident (127) variants are both worse.
//   FETCH pinned ~383 MB (compulsory per-XCD refetch), rate pinned 3.4-3.9 TB/s
//   => random-512B-gather roofline. Do not restructure spmm without a byte cut.
// - DO NOT fuse colsum->sigmoid via atomicAdd into a 256-float region:
//   320K far-atomics serialize ~160 us (R3 disaster).
// - R5: dp_both (fused 2-pass GEMM) + 16-elem prep + sigv_fused = +17 us net
//   regression; launch-gap savings unmeasurable => gaps are SMALL. Reverted.
// - R6: spmm split 3-way as a DIAGNOSTIC (lowers top-5 visibility threshold
//   113 -> ~38 us) to expose the true second-largest kernel with counters.
//   R4-exact bodies otherwise (proven 334.6).

// ---------- bf16 bit helpers ----------
__device__ __forceinline__ float b2f(unsigned short s) {
    union { unsigned int u; float f; } c; c.u = ((unsigned int)s) << 16; return c.f;
}
__device__ __forceinline__ unsigned short f2b(float f) {
    union { float f; unsigned int u; } c; c.f = f;
    unsigned int u = c.u;
    unsigned int r = u + 0x7FFFu + ((u >> 16) & 1u);   // RNE
    return (unsigned short)(r >> 16);
}
__device__ __forceinline__ unsigned int pack2(float lo, float hi) {
    return ((unsigned int)f2b(hi) << 16) | f2b(lo);
}
__device__ __forceinline__ void fma8(float* a, float v, uint4 w) {
    a[0] = fmaf(v, b2f((unsigned short)w.x), a[0]);
    a[1] = fmaf(v, b2f((unsigned short)(w.x >> 16)), a[1]);
    a[2] = fmaf(v, b2f((unsigned short)w.y), a[2]);
    a[3] = fmaf(v, b2f((unsigned short)(w.y >> 16)), a[3]);
    a[4] = fmaf(v, b2f((unsigned short)w.z), a[4]);
    a[5] = fmaf(v, b2f((unsigned short)(w.z >> 16)), a[5]);
    a[6] = fmaf(v, b2f((unsigned short)w.w), a[6]);
    a[7] = fmaf(v, b2f((unsigned short)(w.w >> 16)), a[7]);
}

typedef __attribute__((ext_vector_type(8))) short bf16x8;
typedef __attribute__((ext_vector_type(4))) float f32x4;

#define T_TILES 5

// ---------- K1: fused prep: rowptr | W1 -> bf16 | x/x_tilde -> interleaved bf16 ----------
// xint layout: node row = 512 B: [x 128 bf16][x_tilde 128 bf16]
__global__ __launch_bounds__(256) void prep(
    const int* __restrict__ row, int* __restrict__ rp, int n, int e, int rb,
    const float* __restrict__ w1, unsigned short* __restrict__ w1b, int pb,
    const float* __restrict__ x, const float* __restrict__ xt,
    unsigned short* __restrict__ xint, int total8, int halfcb)
{
    int b = blockIdx.x, tid = threadIdx.x;
    if (b < rb) {                                   // --- build row_ptr ---
        int i = b * 256 + tid;
        if (i > e) return;
        if (i == 0) {
            int r1 = row[0];
            for (int rr = 0; rr <= r1; ++rr) rp[rr] = 0;
        } else if (i == e) {
            int r0 = row[e - 1];
            for (int rr = r0 + 1; rr <= n; ++rr) rp[rr] = e;
        } else {
            int r0 = row[i - 1], r1 = row[i];
            for (int rr = r0 + 1; rr <= r1; ++rr) rp[rr] = i;
        }
    } else if (b < rb + pb) {                       // --- W1 -> bf16 ---
        int i = (b - rb) * 256 + tid;               // 0..32767
        if (i < 32768) w1b[i] = f2b(w1[i]);
    } else {                                        // --- x conversion (interleaved) ---
        int cb = b - rb - pb;
        int which = (cb >= halfcb) ? 1 : 0;
        int i = (cb - which * halfcb) * 256 + tid;  // 8-elem chunk index
        if (i >= total8) return;
        const float* s = which ? xt : x;
        int node = i >> 4, sub = i & 15;
        const float4* p = (const float4*)s + (size_t)i * 2;
        float4 a = p[0], bb = p[1];
        uint4 o;
        o.x = pack2(a.x, a.y);  o.y = pack2(a.z, a.w);
        o.z = pack2(bb.x, bb.y); o.w = pack2(bb.z, bb.w);
        *(uint4*)(xint + (size_t)node * 256 + which * 128 + sub * 8) = o;
    }
}

// ---------- K2: dual SpMM; col/vals preloaded per 64-edge chunk, 16 edges/iter ----------
// lane = g*16 + l: group g handles edges {base+4u+g}, lane l handles dims [8l,8l+8)
// PROVEN BEST body (113 us single-launch). Launched in 3 row-range chunks this
// round as a top-5 visibility diagnostic.
__global__ __launch_bounds__(256) void spmm_dual4(
    const unsigned short* __restrict__ xint, const float* __restrict__ vals,
    const int* __restrict__ col, const int* __restrict__ row_ptr,
    unsigned short* __restrict__ aggx, unsigned short* __restrict__ aggt,
    int r_base, int r_end)
{
    int wave = threadIdx.x >> 6;
    int lane = threadIdx.x & 63;
    int g = lane >> 4, l = lane & 15;
    int r = r_base + blockIdx.x * 4 + wave;
    if (r >= r_end) return;
    int e0 = row_ptr[r], e1 = row_ptr[r + 1];
    float ax[8], at[8];
#pragma unroll
    for (int d = 0; d < 8; ++d) { ax[d] = 0.f; at[d] = 0.f; }
    for (int chunk = e0; chunk < e1; chunk += 64) {
        int m = e1 - chunk; if (m > 64) m = 64;     // edges in this chunk
        int ce = chunk + (lane < m ? lane : m - 1); // coalesced preload (clamped)
        int cc = col[ce];
        float cv = (lane < m) ? vals[ce] : 0.f;
        for (int base = 0; base < m; base += 16) {
            uint4 xw[4], tw[4];
            float fv[4];
#pragma unroll
            for (int u = 0; u < 4; ++u) {
                int idx = base + 4 * u + g;
                int idc = idx < m ? idx : m - 1;    // clamp: duplicate line is cache-hot
                int c  = __shfl(cc, idc, 64);
                float v = __shfl(cv, idc, 64);
                fv[u] = (idx < m) ? v : 0.f;
                const uint4* p = (const uint4*)(xint + (size_t)c * 256);
                xw[u] = p[l];
                tw[u] = p[16 + l];
            }
#pragma unroll
            for (int u = 0; u < 4; ++u) { fma8(ax, fv[u], xw[u]); fma8(at, fv[u], tw[u]); }
        }
    }
#pragma unroll
    for (int d = 0; d < 8; ++d) {
        ax[d] += __shfl_xor(ax[d], 16, 64);
        ax[d] += __shfl_xor(ax[d], 32, 64);
        at[d] += __shfl_xor(at[d], 16, 64);
        at[d] += __shfl_xor(at[d], 32, 64);
    }
    if (g == 0) {
        uint4 o;
        o.x = pack2(ax[0], ax[1]); o.y = pack2(ax[2], ax[3]);
        o.z = pack2(ax[4], ax[5]); o.w = pack2(ax[6], ax[7]);
        ((uint4*)(aggx + (size_t)r * 128))[l] = o;
    } else if (g == 1) {
        uint4 o;
        o.x = pack2(at[0], at[1]); o.y = pack2(at[2], at[3]);
        o.z = pack2(at[4], at[5]); o.w = pack2(at[6], at[7]);
        ((uint4*)(aggt + (size_t)r * 128))[l] = o;
    }
}

// ---------- K3: GEMM + colsum; W1 resident; transposed atomic-free partials ----------
// C/D layout: col = nl, row = quad*4 + r. Column sum => sum over r, then quad bits.
// partial layout: [out_dim 256][block nb]  (coalesced for the reducer)
__global__ __launch_bounds__(256) void gemm_colsum3(
    const short* __restrict__ aggb, const short* __restrict__ w1,
    const float* __restrict__ pa, float* __restrict__ partial, int ntiles, int nb)
{
    int tid = threadIdx.x;
    int w = tid >> 6, lane = tid & 63;
    int nl = lane & 15, quad = lane >> 4;
    const short* brow = w1 + ((size_t)(4 * w) * 16 + nl) * 128 + quad * 8;
    bf16x8 bf[4][4];
#pragma unroll
    for (int j = 0; j < 4; ++j)
#pragma unroll
        for (int k = 0; k < 4; ++k)
            bf[j][k] = *(const bf16x8*)(brow + j * 2048 + k * 32);
    float aslope = pa[0];
    float cs[4] = {0.f, 0.f, 0.f, 0.f};
    int t0 = blockIdx.x * T_TILES;
    int nt = ntiles - t0; if (nt > T_TILES) nt = T_TILES;
    for (int i = 0; i < nt; ++i) {
        const short* arow = aggb + ((size_t)(t0 + i) * 16 + nl) * 128 + quad * 8;
        bf16x8 af[4];
#pragma unroll
        for (int k = 0; k < 4; ++k) af[k] = *(const bf16x8*)(arow + k * 32);
        f32x4 acc[4];
#pragma unroll
        for (int j = 0; j < 4; ++j) acc[j] = (f32x4){0.f, 0.f, 0.f, 0.f};
#pragma unroll
        for (int k = 0; k < 4; ++k)
#pragma unroll
            for (int j = 0; j < 4; ++j)
                acc[j] = __builtin_amdgcn_mfma_f32_16x16x32_bf16(af[k], bf[j][k], acc[j], 0, 0, 0);
#pragma unroll
        for (int j = 0; j < 4; ++j)
#pragma unroll
            for (int r = 0; r < 4; ++r) {
                float z = acc[j][r];
                cs[j] += (z >= 0.f) ? z : aslope * z;
            }
    }
#pragma unroll
    for (int j = 0; j < 4; ++j) {
        cs[j] += __shfl_xor(cs[j], 16, 64);   // reduce rows: quad bits only
        cs[j] += __shfl_xor(cs[j], 32, 64);
    }
    if (quad == 0)
#pragma unroll
        for (int j = 0; j < 4; ++j)
            partial[(size_t)((4 * w + j) * 16 + nl) * nb + blockIdx.x] = cs[j];
}

// ---------- K4: reduce partials + sigmoid -> s (one block per out dim) ----------
__global__ __launch_bounds__(256) void reduce_sig(
    const float* __restrict__ partial, int nb, float* __restrict__ s_out, float invN)
{
    __shared__ float l[256];
    int d = blockIdx.x, tid = threadIdx.x;
    float s = 0.f;
    for (int i = tid; i < nb; i += 256)
        s += partial[(size_t)d * nb + i];
    l[tid] = s;
    __syncthreads();
    for (int o = 128; o > 0; o >>= 1) {
        if (tid < o) l[tid] += l[tid + o];
        __syncthreads();
    }
    if (tid == 0) s_out[d] = 1.f / (1.f + expf(-l[0] * invN));
}

// ---------- K5: v = w_bil @ s (one block per output dim, wave reduce) ----------
__global__ __launch_bounds__(64) void compute_v2(
    const float* __restrict__ s_in, const float* __restrict__ wbil,
    float* __restrict__ v)
{
    int d = blockIdx.x;
    int lane = threadIdx.x;
    const float* wrow = wbil + (size_t)d * 256;
    float acc = 0.f;
#pragma unroll
    for (int j = 0; j < 4; ++j)
        acc = fmaf(wrow[j * 64 + lane], s_in[j * 64 + lane], acc);
    acc += __shfl_xor(acc, 1, 64);
    acc += __shfl_xor(acc, 2, 64);
    acc += __shfl_xor(acc, 4, 64);
    acc += __shfl_xor(acc, 8, 64);
    acc += __shfl_xor(acc, 16, 64);
    acc += __shfl_xor(acc, 32, 64);
    if (lane == 0) v[d] = acc;
}

// ---------- K6: GEMM + dot with v; W1 resident; LDS cross-wave reduce ----------
__global__ __launch_bounds__(256) void gemm_dp2(
    const short* __restrict__ aggx, const short* __restrict__ aggt,
    const short* __restrict__ w1, const float* __restrict__ pa,
    const float* __restrict__ v, float* __restrict__ out, int ntiles, int N)
{
    __shared__ float dpbuf[4][T_TILES * 16];
    int tid = threadIdx.x;
    int w = tid >> 6, lane = tid & 63;
    int nl = lane & 15, quad = lane >> 4;
    const short* agg = blockIdx.y ? aggt : aggx;
    const short* brow = w1 + ((size_t)(4 * w) * 16 + nl) * 128 + quad * 8;
    bf16x8 bf[4][4];
#pragma unroll
    for (int j = 0; j < 4; ++j)
#pragma unroll
        for (int k = 0; k < 4; ++k)
            bf[j][k] = *(const bf16x8*)(brow + j * 2048 + k * 32);
    float vreg[4];
#pragma unroll
    for (int j = 0; j < 4; ++j) vreg[j] = v[(4 * w + j) * 16 + nl];
    float aslope = pa[0];
    int t0 = blockIdx.x * T_TILES;
    int nt = ntiles - t0; if (nt > T_TILES) nt = T_TILES;
    for (int i = 0; i < nt; ++i) {
        const short* arow = agg + ((size_t)(t0 + i) * 16 + nl) * 128 + quad * 8;
        bf16x8 af[4];
#pragma unroll
        for (int k = 0; k < 4; ++k) af[k] = *(const bf16x8*)(arow + k * 32);
        f32x4 acc[4];
#pragma unroll
        for (int j = 0; j < 4; ++j) acc[j] = (f32x4){0.f, 0.f, 0.f, 0.f};
#pragma unroll
        for (int k = 0; k < 4; ++k)
#pragma unroll
            for (int j = 0; j < 4; ++j)
                acc[j] = __builtin_amdgcn_mfma_f32_16x16x32_bf16(af[k], bf[j][k], acc[j], 0, 0, 0);
        float p[4] = {0.f, 0.f, 0.f, 0.f};
#pragma unroll
        for (int j = 0; j < 4; ++j)
#pragma unroll
            for (int r = 0; r < 4; ++r) {
                float z = acc[j][r];
                float h = (z >= 0.f) ? z : aslope * z;
                p[r] = fmaf(h, vreg[j], p[r]);
            }
#pragma unroll
        for (int r = 0; r < 4; ++r) {   // reduce over nl bits (16 cols of the slice)
            p[r] += __shfl_xor(p[r], 1, 64);
            p[r] += __shfl_xor(p[r], 2, 64);
            p[r] += __shfl_xor(p[r], 4, 64);
            p[r] += __shfl_xor(p[r], 8, 64);
        }
        if (nl == 0)
#pragma unroll
            for (int r = 0; r < 4; ++r)
                dpbuf[w][i * 16 + quad * 4 + r] = p[r];
    }
    __syncthreads();
    int nloc = nt * 16;
    for (int idx = tid; idx < nloc; idx += 256) {
        float s = dpbuf[0][idx] + dpbuf[1][idx] + dpbuf[2][idx] + dpbuf[3][idx];
        out[(size_t)blockIdx.y * N + (size_t)t0 * 16 + idx] = s;
    }
}

extern "C" void kernel_launch(void* const* d_in, const int* in_sizes, int n_in,
                              void* d_out, int out_size, void* d_ws, size_t ws_size,
                              hipStream_t stream) {
    const float* x    = (const float*)d_in[0];
    const float* xt   = (const float*)d_in[1];
    const float* vals = (const float*)d_in[2];
    const int* row    = (const int*)d_in[3];
    const int* col    = (const int*)d_in[4];
    const float* w1   = (const float*)d_in[5];
    const float* pa   = (const float*)d_in[6];
    const float* wb   = (const float*)d_in[7];

    const int N = in_sizes[0] / 128;
    const int E = in_sizes[2];
    const int ntiles = (N + 15) / 16;
    const int cs_blocks = (ntiles + T_TILES - 1) / T_TILES;

    char* ws = (char*)d_ws;
    size_t off = 0;
    auto alloc = [&](size_t bytes) { char* p = ws + off; off = (off + bytes + 255) & ~(size_t)255; return p; };
    int* row_ptr         = (int*)alloc((size_t)(N + 1) * 4);
    unsigned short* aggx = (unsigned short*)alloc((size_t)N * 128 * 2);
    unsigned short* aggt = (unsigned short*)alloc((size_t)N * 128 * 2);
    unsigned short* w1b  = (unsigned short*)alloc(32768 * 2);
    float* partial       = (float*)alloc((size_t)cs_blocks * 256 * 4);
    float* svec          = (float*)alloc(256 * 4);
    float* vvec          = (float*)alloc(256 * 4);
    unsigned short* xint = (unsigned short*)alloc((size_t)N * 256 * 2);  // x|xt interleaved bf16

    int rb = (E + 1 + 255) / 256;
    int pb = 128;
    int total8 = (N * 128) / 8;
    int halfcb = (total8 + 255) / 256;
    prep<<<rb + pb + 2 * halfcb, 256, 0, stream>>>(
        row, row_ptr, N, E, rb, w1, w1b, pb, x, xt, xint, total8, halfcb);

    // DIAGNOSTIC split: 3 row-range chunks (~38 us each) so any other kernel
    // above ~38 us becomes visible in the top-5 dispatch table.
    int chunk = ((N + 2) / 3 + 3) & ~3;             // multiple of 4 rows
    for (int c0 = 0; c0 < N; c0 += chunk) {
        int c1 = c0 + chunk; if (c1 > N) c1 = N;
        int nblk = (c1 - c0 + 3) / 4;
        spmm_dual4<<<nblk, 256, 0, stream>>>(
            xint, vals, col, row_ptr, aggx, aggt, c0, c1);
    }

    gemm_colsum3<<<cs_blocks, 256, 0, stream>>>(
        (const short*)aggx, (const short*)w1b, pa, partial, ntiles, cs_blocks);
    reduce_sig<<<256, 256, 0, stream>>>(partial, cs_blocks, svec, 1.0f / (float)N);
    compute_v2<<<256, 64, 0, stream>>>(svec, wb, vvec);
    gemm_dp2<<<dim3(cs_blocks, 2), 256, 0, stream>>>(
        (const short*)aggx, (const short*)aggt, (const short*)w1b, pa, vvec,
        (float*)d_out, ntiles, N);
}

// Round 7
// 332.449 us; speedup vs baseline: 1.0567x; 1.0350x over previous
//
#include <hip/hip_runtime.h>

// Inputs are f32 (verified: R2-R5 passed via runtime-detect f32 path; reference
// declares float32 and output absmax matched at f32 write-back). bf16 staging
// internally; f32 accumulate; f32 out.
//
// Session notes:
// - spmm_dual4 (1 row/wave, wave-uniform) = 113 us proven best; group/persistent
//   variants worse. FETCH pinned ~383 MB, rate pinned 3.4-3.9 TB/s =>
//   random-512B-gather roofline. Do not restructure spmm without a byte cut.
// - DO NOT fuse colsum->sigmoid via atomicAdd into a 256-float region (R3:
//   320K far-atomics serialize ~160 us).
// - R5: dp_both + 16-elem prep + sigv_fused = +17 us net; reverted.
// - R6 diagnostic: gemm_dp2 ~49 us (90% stalled; MfmaUtil 10% == FLOP-rate
//   ratio), prep ~49 us, colsum ~25 us. dp2/colsum theory: cross-XCD L3
//   latency on agg tile loads, no overlap across tiles.
// - R7: register double-buffer prefetch in both GEMM kernels (one lever each).

// ---------- bf16 bit helpers ----------
__device__ __forceinline__ float b2f(unsigned short s) {
    union { unsigned int u; float f; } c; c.u = ((unsigned int)s) << 16; return c.f;
}
__device__ __forceinline__ unsigned short f2b(float f) {
    union { float f; unsigned int u; } c; c.f = f;
    unsigned int u = c.u;
    unsigned int r = u + 0x7FFFu + ((u >> 16) & 1u);   // RNE
    return (unsigned short)(r >> 16);
}
__device__ __forceinline__ unsigned int pack2(float lo, float hi) {
    return ((unsigned int)f2b(hi) << 16) | f2b(lo);
}
__device__ __forceinline__ void fma8(float* a, float v, uint4 w) {
    a[0] = fmaf(v, b2f((unsigned short)w.x), a[0]);
    a[1] = fmaf(v, b2f((unsigned short)(w.x >> 16)), a[1]);
    a[2] = fmaf(v, b2f((unsigned short)w.y), a[2]);
    a[3] = fmaf(v, b2f((unsigned short)(w.y >> 16)), a[3]);
    a[4] = fmaf(v, b2f((unsigned short)w.z), a[4]);
    a[5] = fmaf(v, b2f((unsigned short)(w.z >> 16)), a[5]);
    a[6] = fmaf(v, b2f((unsigned short)w.w), a[6]);
    a[7] = fmaf(v, b2f((unsigned short)(w.w >> 16)), a[7]);
}

typedef __attribute__((ext_vector_type(8))) short bf16x8;
typedef __attribute__((ext_vector_type(4))) float f32x4;

#define T_TILES 5

// ---------- K1: fused prep: rowptr | W1 -> bf16 | x/x_tilde -> interleaved bf16 ----------
// xint layout: node row = 512 B: [x 128 bf16][x_tilde 128 bf16]
__global__ __launch_bounds__(256) void prep(
    const int* __restrict__ row, int* __restrict__ rp, int n, int e, int rb,
    const float* __restrict__ w1, unsigned short* __restrict__ w1b, int pb,
    const float* __restrict__ x, const float* __restrict__ xt,
    unsigned short* __restrict__ xint, int total8, int halfcb)
{
    int b = blockIdx.x, tid = threadIdx.x;
    if (b < rb) {                                   // --- build row_ptr ---
        int i = b * 256 + tid;
        if (i > e) return;
        if (i == 0) {
            int r1 = row[0];
            for (int rr = 0; rr <= r1; ++rr) rp[rr] = 0;
        } else if (i == e) {
            int r0 = row[e - 1];
            for (int rr = r0 + 1; rr <= n; ++rr) rp[rr] = e;
        } else {
            int r0 = row[i - 1], r1 = row[i];
            for (int rr = r0 + 1; rr <= r1; ++rr) rp[rr] = i;
        }
    } else if (b < rb + pb) {                       // --- W1 -> bf16 ---
        int i = (b - rb) * 256 + tid;               // 0..32767
        if (i < 32768) w1b[i] = f2b(w1[i]);
    } else {                                        // --- x conversion (interleaved) ---
        int cb = b - rb - pb;
        int which = (cb >= halfcb) ? 1 : 0;
        int i = (cb - which * halfcb) * 256 + tid;  // 8-elem chunk index
        if (i >= total8) return;
        const float* s = which ? xt : x;
        int node = i >> 4, sub = i & 15;
        const float4* p = (const float4*)s + (size_t)i * 2;
        float4 a = p[0], bb = p[1];
        uint4 o;
        o.x = pack2(a.x, a.y);  o.y = pack2(a.z, a.w);
        o.z = pack2(bb.x, bb.y); o.w = pack2(bb.z, bb.w);
        *(uint4*)(xint + (size_t)node * 256 + which * 128 + sub * 8) = o;
    }
}

// ---------- K2: dual SpMM; col/vals preloaded per 64-edge chunk, 16 edges/iter ----------
// lane = g*16 + l: group g handles edges {base+4u+g}, lane l handles dims [8l,8l+8)
// PROVEN BEST body (113 us single-launch). DO NOT TOUCH.
__global__ __launch_bounds__(256) void spmm_dual4(
    const unsigned short* __restrict__ xint, const float* __restrict__ vals,
    const int* __restrict__ col, const int* __restrict__ row_ptr,
    unsigned short* __restrict__ aggx, unsigned short* __restrict__ aggt,
    int r_base, int r_end)
{
    int wave = threadIdx.x >> 6;
    int lane = threadIdx.x & 63;
    int g = lane >> 4, l = lane & 15;
    int r = r_base + blockIdx.x * 4 + wave;
    if (r >= r_end) return;
    int e0 = row_ptr[r], e1 = row_ptr[r + 1];
    float ax[8], at[8];
#pragma unroll
    for (int d = 0; d < 8; ++d) { ax[d] = 0.f; at[d] = 0.f; }
    for (int chunk = e0; chunk < e1; chunk += 64) {
        int m = e1 - chunk; if (m > 64) m = 64;     // edges in this chunk
        int ce = chunk + (lane < m ? lane : m - 1); // coalesced preload (clamped)
        int cc = col[ce];
        float cv = (lane < m) ? vals[ce] : 0.f;
        for (int base = 0; base < m; base += 16) {
            uint4 xw[4], tw[4];
            float fv[4];
#pragma unroll
            for (int u = 0; u < 4; ++u) {
                int idx = base + 4 * u + g;
                int idc = idx < m ? idx : m - 1;    // clamp: duplicate line is cache-hot
                int c  = __shfl(cc, idc, 64);
                float v = __shfl(cv, idc, 64);
                fv[u] = (idx < m) ? v : 0.f;
                const uint4* p = (const uint4*)(xint + (size_t)c * 256);
                xw[u] = p[l];
                tw[u] = p[16 + l];
            }
#pragma unroll
            for (int u = 0; u < 4; ++u) { fma8(ax, fv[u], xw[u]); fma8(at, fv[u], tw[u]); }
        }
    }
#pragma unroll
    for (int d = 0; d < 8; ++d) {
        ax[d] += __shfl_xor(ax[d], 16, 64);
        ax[d] += __shfl_xor(ax[d], 32, 64);
        at[d] += __shfl_xor(at[d], 16, 64);
        at[d] += __shfl_xor(at[d], 32, 64);
    }
    if (g == 0) {
        uint4 o;
        o.x = pack2(ax[0], ax[1]); o.y = pack2(ax[2], ax[3]);
        o.z = pack2(ax[4], ax[5]); o.w = pack2(ax[6], ax[7]);
        ((uint4*)(aggx + (size_t)r * 128))[l] = o;
    } else if (g == 1) {
        uint4 o;
        o.x = pack2(at[0], at[1]); o.y = pack2(at[2], at[3]);
        o.z = pack2(at[4], at[5]); o.w = pack2(at[6], at[7]);
        ((uint4*)(aggt + (size_t)r * 128))[l] = o;
    }
}

// ---------- K3: GEMM + colsum; W1 resident; register double-buffer prefetch ----------
// C/D layout: col = nl, row = quad*4 + r. Column sum => sum over r, then quad bits.
// partial layout: [out_dim 256][block nb]  (coalesced for the reducer)
__global__ __launch_bounds__(256) void gemm_colsum3(
    const short* __restrict__ aggb, const short* __restrict__ w1,
    const float* __restrict__ pa, float* __restrict__ partial, int ntiles, int nb)
{
    int tid = threadIdx.x;
    int w = tid >> 6, lane = tid & 63;
    int nl = lane & 15, quad = lane >> 4;
    const short* brow = w1 + ((size_t)(4 * w) * 16 + nl) * 128 + quad * 8;
    bf16x8 bf[4][4];
#pragma unroll
    for (int j = 0; j < 4; ++j)
#pragma unroll
        for (int k = 0; k < 4; ++k)
            bf[j][k] = *(const bf16x8*)(brow + j * 2048 + k * 32);
    float aslope = pa[0];
    float cs[4] = {0.f, 0.f, 0.f, 0.f};
    int t0 = blockIdx.x * T_TILES;
    int nt = ntiles - t0; if (nt > T_TILES) nt = T_TILES;
    size_t lanebase = (size_t)nl * 128 + quad * 8;
    // prefetch tile 0
    bf16x8 afA[4];
    {
        const short* arow = aggb + (size_t)t0 * 2048 + lanebase;
#pragma unroll
        for (int k = 0; k < 4; ++k) afA[k] = *(const bf16x8*)(arow + k * 32);
    }
    for (int i = 0; i < nt; ++i) {
        bf16x8 afB[4];
        if (i + 1 < nt) {                           // prefetch next tile
            const short* anext = aggb + (size_t)(t0 + i + 1) * 2048 + lanebase;
#pragma unroll
            for (int k = 0; k < 4; ++k) afB[k] = *(const bf16x8*)(anext + k * 32);
        }
        f32x4 acc[4];
#pragma unroll
        for (int j = 0; j < 4; ++j) acc[j] = (f32x4){0.f, 0.f, 0.f, 0.f};
#pragma unroll
        for (int k = 0; k < 4; ++k)
#pragma unroll
            for (int j = 0; j < 4; ++j)
                acc[j] = __builtin_amdgcn_mfma_f32_16x16x32_bf16(afA[k], bf[j][k], acc[j], 0, 0, 0);
#pragma unroll
        for (int j = 0; j < 4; ++j)
#pragma unroll
            for (int r = 0; r < 4; ++r) {
                float z = acc[j][r];
                cs[j] += (z >= 0.f) ? z : aslope * z;
            }
#pragma unroll
        for (int k = 0; k < 4; ++k) afA[k] = afB[k];
    }
#pragma unroll
    for (int j = 0; j < 4; ++j) {
        cs[j] += __shfl_xor(cs[j], 16, 64);   // reduce rows: quad bits only
        cs[j] += __shfl_xor(cs[j], 32, 64);
    }
    if (quad == 0)
#pragma unroll
        for (int j = 0; j < 4; ++j)
            partial[(size_t)((4 * w + j) * 16 + nl) * nb + blockIdx.x] = cs[j];
}

// ---------- K4: reduce partials + sigmoid -> s (one block per out dim) ----------
__global__ __launch_bounds__(256) void reduce_sig(
    const float* __restrict__ partial, int nb, float* __restrict__ s_out, float invN)
{
    __shared__ float l[256];
    int d = blockIdx.x, tid = threadIdx.x;
    float s = 0.f;
    for (int i = tid; i < nb; i += 256)
        s += partial[(size_t)d * nb + i];
    l[tid] = s;
    __syncthreads();
    for (int o = 128; o > 0; o >>= 1) {
        if (tid < o) l[tid] += l[tid + o];
        __syncthreads();
    }
    if (tid == 0) s_out[d] = 1.f / (1.f + expf(-l[0] * invN));
}

// ---------- K5: v = w_bil @ s (one block per output dim, wave reduce) ----------
__global__ __launch_bounds__(64) void compute_v2(
    const float* __restrict__ s_in, const float* __restrict__ wbil,
    float* __restrict__ v)
{
    int d = blockIdx.x;
    int lane = threadIdx.x;
    const float* wrow = wbil + (size_t)d * 256;
    float acc = 0.f;
#pragma unroll
    for (int j = 0; j < 4; ++j)
        acc = fmaf(wrow[j * 64 + lane], s_in[j * 64 + lane], acc);
    acc += __shfl_xor(acc, 1, 64);
    acc += __shfl_xor(acc, 2, 64);
    acc += __shfl_xor(acc, 4, 64);
    acc += __shfl_xor(acc, 8, 64);
    acc += __shfl_xor(acc, 16, 64);
    acc += __shfl_xor(acc, 32, 64);
    if (lane == 0) v[d] = acc;
}

// ---------- K6: GEMM + dot with v; W1 resident; register double-buffer prefetch ----------
__global__ __launch_bounds__(256) void gemm_dp2(
    const short* __restrict__ aggx, const short* __restrict__ aggt,
    const short* __restrict__ w1, const float* __restrict__ pa,
    const float* __restrict__ v, float* __restrict__ out, int ntiles, int N)
{
    __shared__ float dpbuf[4][T_TILES * 16];
    int tid = threadIdx.x;
    int w = tid >> 6, lane = tid & 63;
    int nl = lane & 15, quad = lane >> 4;
    const short* agg = blockIdx.y ? aggt : aggx;
    const short* brow = w1 + ((size_t)(4 * w) * 16 + nl) * 128 + quad * 8;
    bf16x8 bf[4][4];
#pragma unroll
    for (int j = 0; j < 4; ++j)
#pragma unroll
        for (int k = 0; k < 4; ++k)
            bf[j][k] = *(const bf16x8*)(brow + j * 2048 + k * 32);
    float vreg[4];
#pragma unroll
    for (int j = 0; j < 4; ++j) vreg[j] = v[(4 * w + j) * 16 + nl];
    float aslope = pa[0];
    int t0 = blockIdx.x * T_TILES;
    int nt = ntiles - t0; if (nt > T_TILES) nt = T_TILES;
    size_t lanebase = (size_t)nl * 128 + quad * 8;
    bf16x8 afA[4];
    {
        const short* arow = agg + (size_t)t0 * 2048 + lanebase;
#pragma unroll
        for (int k = 0; k < 4; ++k) afA[k] = *(const bf16x8*)(arow + k * 32);
    }
    for (int i = 0; i < nt; ++i) {
        bf16x8 afB[4];
        if (i + 1 < nt) {                           // prefetch next tile
            const short* anext = agg + (size_t)(t0 + i + 1) * 2048 + lanebase;
#pragma unroll
            for (int k = 0; k < 4; ++k) afB[k] = *(const bf16x8*)(anext + k * 32);
        }
        f32x4 acc[4];
#pragma unroll
        for (int j = 0; j < 4; ++j) acc[j] = (f32x4){0.f, 0.f, 0.f, 0.f};
#pragma unroll
        for (int k = 0; k < 4; ++k)
#pragma unroll
            for (int j = 0; j < 4; ++j)
                acc[j] = __builtin_amdgcn_mfma_f32_16x16x32_bf16(afA[k], bf[j][k], acc[j], 0, 0, 0);
        float p[4] = {0.f, 0.f, 0.f, 0.f};
#pragma unroll
        for (int j = 0; j < 4; ++j)
#pragma unroll
            for (int r = 0; r < 4; ++r) {
                float z = acc[j][r];
                float h = (z >= 0.f) ? z : aslope * z;
                p[r] = fmaf(h, vreg[j], p[r]);
            }
#pragma unroll
        for (int r = 0; r < 4; ++r) {   // reduce over nl bits (16 cols of the slice)
            p[r] += __shfl_xor(p[r], 1, 64);
            p[r] += __shfl_xor(p[r], 2, 64);
            p[r] += __shfl_xor(p[r], 4, 64);
            p[r] += __shfl_xor(p[r], 8, 64);
        }
        if (nl == 0)
#pragma unroll
            for (int r = 0; r < 4; ++r)
                dpbuf[w][i * 16 + quad * 4 + r] = p[r];
#pragma unroll
        for (int k = 0; k < 4; ++k) afA[k] = afB[k];
    }
    __syncthreads();
    int nloc = nt * 16;
    for (int idx = tid; idx < nloc; idx += 256) {
        float s = dpbuf[0][idx] + dpbuf[1][idx] + dpbuf[2][idx] + dpbuf[3][idx];
        out[(size_t)blockIdx.y * N + (size_t)t0 * 16 + idx] = s;
    }
}

extern "C" void kernel_launch(void* const* d_in, const int* in_sizes, int n_in,
                              void* d_out, int out_size, void* d_ws, size_t ws_size,
                              hipStream_t stream) {
    const float* x    = (const float*)d_in[0];
    const float* xt   = (const float*)d_in[1];
    const float* vals = (const float*)d_in[2];
    const int* row    = (const int*)d_in[3];
    const int* col    = (const int*)d_in[4];
    const float* w1   = (const float*)d_in[5];
    const float* pa   = (const float*)d_in[6];
    const float* wb   = (const float*)d_in[7];

    const int N = in_sizes[0] / 128;
    const int E = in_sizes[2];
    const int ntiles = (N + 15) / 16;
    const int cs_blocks = (ntiles + T_TILES - 1) / T_TILES;

    char* ws = (char*)d_ws;
    size_t off = 0;
    auto alloc = [&](size_t bytes) { char* p = ws + off; off = (off + bytes + 255) & ~(size_t)255; return p; };
    int* row_ptr         = (int*)alloc((size_t)(N + 1) * 4);
    unsigned short* aggx = (unsigned short*)alloc((size_t)N * 128 * 2);
    unsigned short* aggt = (unsigned short*)alloc((size_t)N * 128 * 2);
    unsigned short* w1b  = (unsigned short*)alloc(32768 * 2);
    float* partial       = (float*)alloc((size_t)cs_blocks * 256 * 4);
    float* svec          = (float*)alloc(256 * 4);
    float* vvec          = (float*)alloc(256 * 4);
    unsigned short* xint = (unsigned short*)alloc((size_t)N * 256 * 2);  // x|xt interleaved bf16

    int rb = (E + 1 + 255) / 256;
    int pb = 128;
    int total8 = (N * 128) / 8;
    int halfcb = (total8 + 255) / 256;
    prep<<<rb + pb + 2 * halfcb, 256, 0, stream>>>(
        row, row_ptr, N, E, rb, w1, w1b, pb, x, xt, xint, total8, halfcb);

    spmm_dual4<<<(N + 3) / 4, 256, 0, stream>>>(
        xint, vals, col, row_ptr, aggx, aggt, 0, N);

    gemm_colsum3<<<cs_blocks, 256, 0, stream>>>(
        (const short*)aggx, (const short*)w1b, pa, partial, ntiles, cs_blocks);
    reduce_sig<<<256, 256, 0, stream>>>(partial, cs_blocks, svec, 1.0f / (float)N);
    compute_v2<<<256, 64, 0, stream>>>(svec, wb, vvec);
    gemm_dp2<<<dim3(cs_blocks, 2), 256, 0, stream>>>(
        (const short*)aggx, (const short*)aggt, (const short*)w1b, pa, vvec,
        (float*)d_out, ntiles, N);
}

// Round 8
// 313.220 us; speedup vs baseline: 1.1215x; 1.0614x over previous
//
#include <hip/hip_runtime.h>

// Inputs are f32 (verified: R2-R5 passed via runtime-detect f32 path; reference
// declares float32 and output absmax matched at f32 write-back). bf16 staging
// internally; f32 accumulate; f32 out.
//
// Session notes:
// - spmm_dual4 (1 row/wave, wave-uniform) = 113 us proven best; group/persistent
//   variants worse. FETCH pinned ~383 MB, rate pinned 3.4-3.9 TB/s =>
//   random-512B-gather roofline. Do not restructure spmm without a byte cut.
// - DO NOT fuse colsum->sigmoid via atomicAdd into a 256-float region (R3).
// - R5: dp_both + 16-elem prep + sigv_fused = +17 us net; reverted.
// - R6 diagnostic: gemm_dp2 ~49 us (90% stalled), prep ~49 us, colsum ~25 us.
// - R7: depth-1 register prefetch in GEMMs = null (-2 us). Lesson: prefetch
//   hides min(compute,latency); compute ~300cyc << latency ~2000cyc (agg is
//   dirty-remote-L2/HBM). Need DEEP MLP. Also VGPR=60 < 64 needed for bf[4][4]
//   => compiler wasn't keeping W1 frags resident.
// - R8: LDS-stage all 5 agg tiles per block via global_load_lds (async, issued
//   up-front, one barrier), granule-permuted k-major so ds_read_b128 is
//   consecutive per lane (conflict-free, no swizzle needed).

// ---------- bf16 bit helpers ----------
__device__ __forceinline__ float b2f(unsigned short s) {
    union { unsigned int u; float f; } c; c.u = ((unsigned int)s) << 16; return c.f;
}
__device__ __forceinline__ unsigned short f2b(float f) {
    union { float f; unsigned int u; } c; c.f = f;
    unsigned int u = c.u;
    unsigned int r = u + 0x7FFFu + ((u >> 16) & 1u);   // RNE
    return (unsigned short)(r >> 16);
}
__device__ __forceinline__ unsigned int pack2(float lo, float hi) {
    return ((unsigned int)f2b(hi) << 16) | f2b(lo);
}
__device__ __forceinline__ void fma8(float* a, float v, uint4 w) {
    a[0] = fmaf(v, b2f((unsigned short)w.x), a[0]);
    a[1] = fmaf(v, b2f((unsigned short)(w.x >> 16)), a[1]);
    a[2] = fmaf(v, b2f((unsigned short)w.y), a[2]);
    a[3] = fmaf(v, b2f((unsigned short)(w.y >> 16)), a[3]);
    a[4] = fmaf(v, b2f((unsigned short)w.z), a[4]);
    a[5] = fmaf(v, b2f((unsigned short)(w.z >> 16)), a[5]);
    a[6] = fmaf(v, b2f((unsigned short)w.w), a[6]);
    a[7] = fmaf(v, b2f((unsigned short)(w.w >> 16)), a[7]);
}

typedef __attribute__((ext_vector_type(8))) short bf16x8;
typedef __attribute__((ext_vector_type(4))) float f32x4;

#define T_TILES 5

// ---------- K1: fused prep: rowptr | W1 -> bf16 | x/x_tilde -> interleaved bf16 ----------
// xint layout: node row = 512 B: [x 128 bf16][x_tilde 128 bf16]
__global__ __launch_bounds__(256) void prep(
    const int* __restrict__ row, int* __restrict__ rp, int n, int e, int rb,
    const float* __restrict__ w1, unsigned short* __restrict__ w1b, int pb,
    const float* __restrict__ x, const float* __restrict__ xt,
    unsigned short* __restrict__ xint, int total8, int halfcb)
{
    int b = blockIdx.x, tid = threadIdx.x;
    if (b < rb) {                                   // --- build row_ptr ---
        int i = b * 256 + tid;
        if (i > e) return;
        if (i == 0) {
            int r1 = row[0];
            for (int rr = 0; rr <= r1; ++rr) rp[rr] = 0;
        } else if (i == e) {
            int r0 = row[e - 1];
            for (int rr = r0 + 1; rr <= n; ++rr) rp[rr] = e;
        } else {
            int r0 = row[i - 1], r1 = row[i];
            for (int rr = r0 + 1; rr <= r1; ++rr) rp[rr] = i;
        }
    } else if (b < rb + pb) {                       // --- W1 -> bf16 ---
        int i = (b - rb) * 256 + tid;               // 0..32767
        if (i < 32768) w1b[i] = f2b(w1[i]);
    } else {                                        // --- x conversion (interleaved) ---
        int cb = b - rb - pb;
        int which = (cb >= halfcb) ? 1 : 0;
        int i = (cb - which * halfcb) * 256 + tid;  // 8-elem chunk index
        if (i >= total8) return;
        const float* s = which ? xt : x;
        int node = i >> 4, sub = i & 15;
        const float4* p = (const float4*)s + (size_t)i * 2;
        float4 a = p[0], bb = p[1];
        uint4 o;
        o.x = pack2(a.x, a.y);  o.y = pack2(a.z, a.w);
        o.z = pack2(bb.x, bb.y); o.w = pack2(bb.z, bb.w);
        *(uint4*)(xint + (size_t)node * 256 + which * 128 + sub * 8) = o;
    }
}

// ---------- K2: dual SpMM; col/vals preloaded per 64-edge chunk, 16 edges/iter ----------
// lane = g*16 + l: group g handles edges {base+4u+g}, lane l handles dims [8l,8l+8)
// PROVEN BEST body (113 us single-launch). DO NOT TOUCH.
__global__ __launch_bounds__(256) void spmm_dual4(
    const unsigned short* __restrict__ xint, const float* __restrict__ vals,
    const int* __restrict__ col, const int* __restrict__ row_ptr,
    unsigned short* __restrict__ aggx, unsigned short* __restrict__ aggt,
    int r_base, int r_end)
{
    int wave = threadIdx.x >> 6;
    int lane = threadIdx.x & 63;
    int g = lane >> 4, l = lane & 15;
    int r = r_base + blockIdx.x * 4 + wave;
    if (r >= r_end) return;
    int e0 = row_ptr[r], e1 = row_ptr[r + 1];
    float ax[8], at[8];
#pragma unroll
    for (int d = 0; d < 8; ++d) { ax[d] = 0.f; at[d] = 0.f; }
    for (int chunk = e0; chunk < e1; chunk += 64) {
        int m = e1 - chunk; if (m > 64) m = 64;     // edges in this chunk
        int ce = chunk + (lane < m ? lane : m - 1); // coalesced preload (clamped)
        int cc = col[ce];
        float cv = (lane < m) ? vals[ce] : 0.f;
        for (int base = 0; base < m; base += 16) {
            uint4 xw[4], tw[4];
            float fv[4];
#pragma unroll
            for (int u = 0; u < 4; ++u) {
                int idx = base + 4 * u + g;
                int idc = idx < m ? idx : m - 1;    // clamp: duplicate line is cache-hot
                int c  = __shfl(cc, idc, 64);
                float v = __shfl(cv, idc, 64);
                fv[u] = (idx < m) ? v : 0.f;
                const uint4* p = (const uint4*)(xint + (size_t)c * 256);
                xw[u] = p[l];
                tw[u] = p[16 + l];
            }
#pragma unroll
            for (int u = 0; u < 4; ++u) { fma8(ax, fv[u], xw[u]); fma8(at, fv[u], tw[u]); }
        }
    }
#pragma unroll
    for (int d = 0; d < 8; ++d) {
        ax[d] += __shfl_xor(ax[d], 16, 64);
        ax[d] += __shfl_xor(ax[d], 32, 64);
        at[d] += __shfl_xor(at[d], 16, 64);
        at[d] += __shfl_xor(at[d], 32, 64);
    }
    if (g == 0) {
        uint4 o;
        o.x = pack2(ax[0], ax[1]); o.y = pack2(ax[2], ax[3]);
        o.z = pack2(ax[4], ax[5]); o.w = pack2(ax[6], ax[7]);
        ((uint4*)(aggx + (size_t)r * 128))[l] = o;
    } else if (g == 1) {
        uint4 o;
        o.x = pack2(at[0], at[1]); o.y = pack2(at[2], at[3]);
        o.z = pack2(at[4], at[5]); o.w = pack2(at[6], at[7]);
        ((uint4*)(aggt + (size_t)r * 128))[l] = o;
    }
}

// ---------- staging helper: async-copy tile granules k-major into LDS ----------
// Thread t stages global granule (nl=t&15, quad=(t>>4)&3, k=t>>6) of tile i into
// linear LDS slot i*4096 + t*16. Compute-side read for (lane, k) is then at
// (k*64 + lane)*16 bytes -> consecutive per lane, conflict-free ds_read_b128.
__device__ __forceinline__ void stage_tile(
    const short* agg, size_t tile, unsigned short* smem, int i, int tid)
{
    int snl = tid & 15, squad = (tid >> 4) & 3, sk = tid >> 6;
    const unsigned short* src = (const unsigned short*)agg
        + tile * 2048 + (size_t)snl * 128 + squad * 8 + sk * 32;
    __builtin_amdgcn_global_load_lds(
        (const __attribute__((address_space(1))) unsigned int*)src,
        (__attribute__((address_space(3))) unsigned int*)(smem + (size_t)i * 2048 + tid * 8),
        16, 0, 0);
}

// ---------- K3: GEMM + colsum; agg tiles LDS-staged (deep async); W1 in regs ----------
// C/D layout: col = nl, row = quad*4 + r. Column sum => sum over r, then quad bits.
// partial layout: [out_dim 256][block nb]  (coalesced for the reducer)
__global__ __launch_bounds__(256) void gemm_colsum3(
    const short* __restrict__ aggb, const short* __restrict__ w1,
    const float* __restrict__ pa, float* __restrict__ partial, int ntiles, int nb)
{
    __shared__ unsigned short smem[T_TILES * 2048];
    int tid = threadIdx.x;
    int w = tid >> 6, lane = tid & 63;
    int nl = lane & 15, quad = lane >> 4;
    int t0 = blockIdx.x * T_TILES;
    int nt = ntiles - t0; if (nt > T_TILES) nt = T_TILES;
    // issue ALL tile DMAs up-front (deep queue, no VGPR cost)
    for (int i = 0; i < nt; ++i)
        stage_tile(aggb, (size_t)(t0 + i), smem, i, tid);
    // W1 fragment loads overlap the DMA
    const short* brow = w1 + ((size_t)(4 * w) * 16 + nl) * 128 + quad * 8;
    bf16x8 bf[4][4];
#pragma unroll
    for (int j = 0; j < 4; ++j)
#pragma unroll
        for (int k = 0; k < 4; ++k)
            bf[j][k] = *(const bf16x8*)(brow + j * 2048 + k * 32);
    float aslope = pa[0];
    float cs[4] = {0.f, 0.f, 0.f, 0.f};
    __syncthreads();                    // drains vmcnt: DMA + W1 complete
    for (int i = 0; i < nt; ++i) {
        bf16x8 af[4];
#pragma unroll
        for (int k = 0; k < 4; ++k)
            af[k] = *(const bf16x8*)(smem + (size_t)i * 2048 + (k * 64 + lane) * 8);
        f32x4 acc[4];
#pragma unroll
        for (int j = 0; j < 4; ++j) acc[j] = (f32x4){0.f, 0.f, 0.f, 0.f};
#pragma unroll
        for (int k = 0; k < 4; ++k)
#pragma unroll
            for (int j = 0; j < 4; ++j)
                acc[j] = __builtin_amdgcn_mfma_f32_16x16x32_bf16(af[k], bf[j][k], acc[j], 0, 0, 0);
#pragma unroll
        for (int j = 0; j < 4; ++j)
#pragma unroll
            for (int r = 0; r < 4; ++r) {
                float z = acc[j][r];
                cs[j] += (z >= 0.f) ? z : aslope * z;
            }
    }
#pragma unroll
    for (int j = 0; j < 4; ++j) {
        cs[j] += __shfl_xor(cs[j], 16, 64);   // reduce rows: quad bits only
        cs[j] += __shfl_xor(cs[j], 32, 64);
    }
    if (quad == 0)
#pragma unroll
        for (int j = 0; j < 4; ++j)
            partial[(size_t)((4 * w + j) * 16 + nl) * nb + blockIdx.x] = cs[j];
}

// ---------- K4: reduce partials + sigmoid -> s (one block per out dim) ----------
__global__ __launch_bounds__(256) void reduce_sig(
    const float* __restrict__ partial, int nb, float* __restrict__ s_out, float invN)
{
    __shared__ float l[256];
    int d = blockIdx.x, tid = threadIdx.x;
    float s = 0.f;
    for (int i = tid; i < nb; i += 256)
        s += partial[(size_t)d * nb + i];
    l[tid] = s;
    __syncthreads();
    for (int o = 128; o > 0; o >>= 1) {
        if (tid < o) l[tid] += l[tid + o];
        __syncthreads();
    }
    if (tid == 0) s_out[d] = 1.f / (1.f + expf(-l[0] * invN));
}

// ---------- K5: v = w_bil @ s (one block per output dim, wave reduce) ----------
__global__ __launch_bounds__(64) void compute_v2(
    const float* __restrict__ s_in, const float* __restrict__ wbil,
    float* __restrict__ v)
{
    int d = blockIdx.x;
    int lane = threadIdx.x;
    const float* wrow = wbil + (size_t)d * 256;
    float acc = 0.f;
#pragma unroll
    for (int j = 0; j < 4; ++j)
        acc = fmaf(wrow[j * 64 + lane], s_in[j * 64 + lane], acc);
    acc += __shfl_xor(acc, 1, 64);
    acc += __shfl_xor(acc, 2, 64);
    acc += __shfl_xor(acc, 4, 64);
    acc += __shfl_xor(acc, 8, 64);
    acc += __shfl_xor(acc, 16, 64);
    acc += __shfl_xor(acc, 32, 64);
    if (lane == 0) v[d] = acc;
}

// ---------- K6: GEMM + dot with v; agg tiles LDS-staged (deep async) ----------
__global__ __launch_bounds__(256) void gemm_dp2(
    const short* __restrict__ aggx, const short* __restrict__ aggt,
    const short* __restrict__ w1, const float* __restrict__ pa,
    const float* __restrict__ v, float* __restrict__ out, int ntiles, int N)
{
    __shared__ unsigned short smem[T_TILES * 2048];
    __shared__ float dpbuf[4][T_TILES * 16];
    int tid = threadIdx.x;
    int w = tid >> 6, lane = tid & 63;
    int nl = lane & 15, quad = lane >> 4;
    const short* agg = blockIdx.y ? aggt : aggx;
    int t0 = blockIdx.x * T_TILES;
    int nt = ntiles - t0; if (nt > T_TILES) nt = T_TILES;
    // issue ALL tile DMAs up-front
    for (int i = 0; i < nt; ++i)
        stage_tile(agg, (size_t)(t0 + i), smem, i, tid);
    // W1 fragment + v loads overlap the DMA
    const short* brow = w1 + ((size_t)(4 * w) * 16 + nl) * 128 + quad * 8;
    bf16x8 bf[4][4];
#pragma unroll
    for (int j = 0; j < 4; ++j)
#pragma unroll
        for (int k = 0; k < 4; ++k)
            bf[j][k] = *(const bf16x8*)(brow + j * 2048 + k * 32);
    float vreg[4];
#pragma unroll
    for (int j = 0; j < 4; ++j) vreg[j] = v[(4 * w + j) * 16 + nl];
    float aslope = pa[0];
    __syncthreads();                    // drains vmcnt: DMA + W1 + v complete
    for (int i = 0; i < nt; ++i) {
        bf16x8 af[4];
#pragma unroll
        for (int k = 0; k < 4; ++k)
            af[k] = *(const bf16x8*)(smem + (size_t)i * 2048 + (k * 64 + lane) * 8);
        f32x4 acc[4];
#pragma unroll
        for (int j = 0; j < 4; ++j) acc[j] = (f32x4){0.f, 0.f, 0.f, 0.f};
#pragma unroll
        for (int k = 0; k < 4; ++k)
#pragma unroll
            for (int j = 0; j < 4; ++j)
                acc[j] = __builtin_amdgcn_mfma_f32_16x16x32_bf16(af[k], bf[j][k], acc[j], 0, 0, 0);
        float p[4] = {0.f, 0.f, 0.f, 0.f};
#pragma unroll
        for (int j = 0; j < 4; ++j)
#pragma unroll
            for (int r = 0; r < 4; ++r) {
                float z = acc[j][r];
                float h = (z >= 0.f) ? z : aslope * z;
                p[r] = fmaf(h, vreg[j], p[r]);
            }
#pragma unroll
        for (int r = 0; r < 4; ++r) {   // reduce over nl bits (16 cols of the slice)
            p[r] += __shfl_xor(p[r], 1, 64);
            p[r] += __shfl_xor(p[r], 2, 64);
            p[r] += __shfl_xor(p[r], 4, 64);
            p[r] += __shfl_xor(p[r], 8, 64);
        }
        if (nl == 0)
#pragma unroll
            for (int r = 0; r < 4; ++r)
                dpbuf[w][i * 16 + quad * 4 + r] = p[r];
    }
    __syncthreads();
    int nloc = nt * 16;
    for (int idx = tid; idx < nloc; idx += 256) {
        float s = dpbuf[0][idx] + dpbuf[1][idx] + dpbuf[2][idx] + dpbuf[3][idx];
        out[(size_t)blockIdx.y * N + (size_t)t0 * 16 + idx] = s;
    }
}

extern "C" void kernel_launch(void* const* d_in, const int* in_sizes, int n_in,
                              void* d_out, int out_size, void* d_ws, size_t ws_size,
                              hipStream_t stream) {
    const float* x    = (const float*)d_in[0];
    const float* xt   = (const float*)d_in[1];
    const float* vals = (const float*)d_in[2];
    const int* row    = (const int*)d_in[3];
    const int* col    = (const int*)d_in[4];
    const float* w1   = (const float*)d_in[5];
    const float* pa   = (const float*)d_in[6];
    const float* wb   = (const float*)d_in[7];

    const int N = in_sizes[0] / 128;
    const int E = in_sizes[2];
    const int ntiles = (N + 15) / 16;
    const int cs_blocks = (ntiles + T_TILES - 1) / T_TILES;

    char* ws = (char*)d_ws;
    size_t off = 0;
    auto alloc = [&](size_t bytes) { char* p = ws + off; off = (off + bytes + 255) & ~(size_t)255; return p; };
    int* row_ptr         = (int*)alloc((size_t)(N + 1) * 4);
    unsigned short* aggx = (unsigned short*)alloc((size_t)N * 128 * 2);
    unsigned short* aggt = (unsigned short*)alloc((size_t)N * 128 * 2);
    unsigned short* w1b  = (unsigned short*)alloc(32768 * 2);
    float* partial       = (float*)alloc((size_t)cs_blocks * 256 * 4);
    float* svec          = (float*)alloc(256 * 4);
    float* vvec          = (float*)alloc(256 * 4);
    unsigned short* xint = (unsigned short*)alloc((size_t)N * 256 * 2);  // x|xt interleaved bf16

    int rb = (E + 1 + 255) / 256;
    int pb = 128;
    int total8 = (N * 128) / 8;
    int halfcb = (total8 + 255) / 256;
    prep<<<rb + pb + 2 * halfcb, 256, 0, stream>>>(
        row, row_ptr, N, E, rb, w1, w1b, pb, x, xt, xint, total8, halfcb);

    spmm_dual4<<<(N + 3) / 4, 256, 0, stream>>>(
        xint, vals, col, row_ptr, aggx, aggt, 0, N);

    gemm_colsum3<<<cs_blocks, 256, 0, stream>>>(
        (const short*)aggx, (const short*)w1b, pa, partial, ntiles, cs_blocks);
    reduce_sig<<<256, 256, 0, stream>>>(partial, cs_blocks, svec, 1.0f / (float)N);
    compute_v2<<<256, 64, 0, stream>>>(svec, wb, vvec);
    gemm_dp2<<<dim3(cs_blocks, 2), 256, 0, stream>>>(
        (const short*)aggx, (const short*)aggt, (const short*)w1b, pa, vvec,
        (float*)d_out, ntiles, N);
}